// Round 14
// baseline (455.690 us; speedup 1.0000x reference)
//
#include <hip/hip_runtime.h>
#include <hip/hip_fp16.h>

typedef float   f32x4   __attribute__((ext_vector_type(4)));
typedef float   f32x2   __attribute__((ext_vector_type(2)));
typedef float   f32x16  __attribute__((ext_vector_type(16)));
typedef short   short8v __attribute__((ext_vector_type(8)));
typedef unsigned short ushort8v __attribute__((ext_vector_type(8)));
typedef unsigned int   u32x4v __attribute__((ext_vector_type(4)));
typedef unsigned int   u32x2v __attribute__((ext_vector_type(2)));
typedef int     int2v   __attribute__((ext_vector_type(2)));
typedef int     int4v   __attribute__((ext_vector_type(4)));
typedef unsigned int   u32;
typedef unsigned short u16;

#define DEVI static __device__ __forceinline__

DEVI u16 f2bf(float f) {
    u32 u = __builtin_bit_cast(u32, f);
    u += 0x7FFFu + ((u >> 16) & 1u);   // RNE (inputs finite)
    return (u16)(u >> 16);
}
DEVI float bf2f(u16 h) { return __builtin_bit_cast(float, (u32)h << 16); }

// async global->LDS, 16B per lane; lds ptr must be wave-uniform (lane*16 added by HW)
DEVI void gl_lds16(const u16* g, u16* l) {
    __builtin_amdgcn_global_load_lds(
        (const __attribute__((address_space(1))) u32*)(const void*)g,
        (__attribute__((address_space(3))) u32*)(void*)l, 16, 0, 0);
}

// ---------------------------------------------------------------------------
// fused convert of 4 matrices: x->xb, Wq*rscale->wb3, Wk->wb3+4M, Wv->wb3+8M.
// ---------------------------------------------------------------------------
__global__ __launch_bounds__(256) void convert4_kernel(
    const float* __restrict__ x, const float* __restrict__ Wq,
    const float* __restrict__ Wk, const float* __restrict__ Wv,
    u16* __restrict__ xb, u16* __restrict__ wb3, float rscale) {
    const int seg = blockIdx.x >> 11;
    const int idx = (blockIdx.x & 2047) * 256 + threadIdx.x;
    const float* src; u16* dst; float scale = 1.0f;
    if (seg == 0)      { src = x;  dst = xb; }
    else if (seg == 1) { src = Wq; dst = wb3; scale = rscale; }
    else if (seg == 2) { src = Wk; dst = wb3 + 4194304; }
    else               { src = Wv; dst = wb3 + 8388608; }
    const float* p = src + (size_t)idx * 8;
    f32x4 a = *(const f32x4*)p, b = *(const f32x4*)(p + 4);
    ushort8v o;
    o[0]=f2bf(a[0]*scale); o[1]=f2bf(a[1]*scale); o[2]=f2bf(a[2]*scale); o[3]=f2bf(a[3]*scale);
    o[4]=f2bf(b[0]*scale); o[5]=f2bf(b[1]*scale); o[6]=f2bf(b[2]*scale); o[7]=f2bf(b[3]*scale);
    *(ushort8v*)(dst + (size_t)idx * 8) = o;
}

// ---------------------------------------------------------------------------
// prep body: dequant cache -> bf16 K rows + bf16 V^T cols + exact requant.
// pid in 0..4095. Uses 17408 B of LB.
// ---------------------------------------------------------------------------
DEVI void prep_body(int pid, char* LB,
    const int* __restrict__ kq, const int* __restrict__ vq,
    const float* __restrict__ ks, const float* __restrict__ vs,
    u16* __restrict__ kcb, u16* __restrict__ vt,
    float* __restrict__ oktq, float* __restrict__ ovtq,
    float* __restrict__ oksc, float* __restrict__ ovsc) {
    u16 (*Vs)[132] = (u16(*)[132])LB;            // 64*132*2 = 16896 B
    float* skL = (float*)(LB + 16896);
    float* svL = (float*)(LB + 17152);
    const int tid = threadIdx.x;
    const int bh = pid >> 6, kt = pid & 63;
    const int key0 = kt << 6;
    const size_t rowbase = (size_t)bh * 4096 + key0;
    if (tid < 64) { skL[tid] = ks[rowbase + tid]; svL[tid] = vs[rowbase + tid]; }
    __syncthreads();
    const int lane = tid & 63, w = tid >> 6;
    const int q31 = lane & 31, rh = lane >> 5;
    u32x2v* kcw = (u32x2v*)kcb;
    #pragma unroll 4
    for (int s = 0; s < 8; ++s) {
        const int key = s * 8 + w * 2 + rh;
        const size_t row = rowbase + key;
        const float sk = skL[key], sv = svL[key];
        int4v kv = *(const int4v*)(kq + row * 128 + q31 * 4);
        int4v vv = *(const int4v*)(vq + row * 128 + q31 * 4);
        f32x4 kx, vx;
        #pragma unroll
        for (int e = 0; e < 4; ++e) { kx[e] = (float)kv[e] * sk; vx[e] = (float)vv[e] * sv; }
        u32x2v kp, vp;
        kp[0] = (u32)f2bf(kx[0]) | ((u32)f2bf(kx[1]) << 16);
        kp[1] = (u32)f2bf(kx[2]) | ((u32)f2bf(kx[3]) << 16);
        vp[0] = (u32)f2bf(vx[0]) | ((u32)f2bf(vx[1]) << 16);
        vp[1] = (u32)f2bf(vx[2]) | ((u32)f2bf(vx[3]) << 16);
        kcw[(size_t)(bh * 4608 + key0 + key) * 32 + q31] = kp;
        *(u32x2v*)&Vs[key][q31 * 4] = vp;
        float kam = fmaxf(fmaxf(fabsf(kx[0]), fabsf(kx[1])), fmaxf(fabsf(kx[2]), fabsf(kx[3])));
        float vam = fmaxf(fmaxf(fabsf(vx[0]), fabsf(vx[1])), fmaxf(fabsf(vx[2]), fabsf(vx[3])));
        #pragma unroll
        for (int off = 1; off < 32; off <<= 1) {
            kam = fmaxf(kam, __shfl_xor(kam, off, 64));
            vam = fmaxf(vam, __shfl_xor(vam, off, 64));
        }
        const int r = key0 + key;
        if (r >= 512) {
            const size_t orow = (size_t)bh * 4096 + (size_t)(r - 512);
            float kscale = fmaxf(kam / 127.0f, 1e-8f);
            float vscale = fmaxf(vam / 127.0f, 1e-8f);
            float kinv = 1.0f / kscale, vinv = 1.0f / vscale;
            f32x4 ko, vo;
            #pragma unroll
            for (int e = 0; e < 4; ++e) {
                ko[e] = fminf(fmaxf(rintf(kx[e] * kinv), -127.f), 127.f);
                vo[e] = fminf(fmaxf(rintf(vx[e] * vinv), -127.f), 127.f);
            }
            *(f32x4*)(oktq + orow * 128 + q31 * 4) = ko;
            *(f32x4*)(ovtq + orow * 128 + q31 * 4) = vo;
            if (q31 == 0) {
                oksc[orow] = __half2float(__float2half(kscale));
                ovsc[orow] = __half2float(__float2half(vscale));
            }
        }
    }
    __syncthreads();
    const int d = tid >> 1, half = tid & 1;
    u16* obase = vt + ((size_t)bh * 128 + d) * 4608 + key0 + half * 32;
    #pragma unroll
    for (int c = 0; c < 4; ++c) {
        ushort8v tv;
        #pragma unroll
        for (int e = 0; e < 8; ++e) tv[e] = Vs[half * 32 + c * 8 + e][d];
        *(ushort8v*)(obase + c * 8) = tv;
    }
}

// ---------------------------------------------------------------------------
// qkv body: SINGLE-buffered (24KB LDS) so the fused kernel fits 6 blocks/CU;
// block-level TLP replaces the double buffer. BM=128 BN=64 BK=64.
// ---------------------------------------------------------------------------
DEVI void qkv_body(int qid, char* LB,
    const u16* __restrict__ A, const u16* __restrict__ Bw,
    u16* __restrict__ qbf, u16* __restrict__ kcb, u16* __restrict__ vnb) {
    u16* As = (u16*)LB;            // 8192 u16 = 16384 B
    u16* Bs = (u16*)(LB + 16384);  // 4096 u16 = 8192 B
    const int tid = threadIdx.x, lane = tid & 63, w = tid >> 6;
    const int sid = (qid & 7) * 192 + (qid >> 3);
    const int bm = sid & 15, bn = sid >> 4;
    const int m0 = bm * 128, n0 = bn * 64;
    const int wm = (w >> 1) * 64, wn = (w & 1) * 32;
    const int r16 = lane & 15, kb = lane >> 4;

    f32x4 acc[4][2] = {};

    for (int t = 0; t < 32; ++t) {
        const int k0 = t * 64;
        #pragma unroll
        for (int i = 0; i < 4; ++i) {
            int s = i * 256 + tid;
            int row = s >> 3, l = (s & 7) ^ (row & 7);
            gl_lds16(A + (size_t)(m0 + row) * 2048 + k0 + l * 8,
                     &As[(i * 256 + (tid & ~63)) * 8]);
        }
        #pragma unroll
        for (int i = 0; i < 2; ++i) {
            int s = i * 256 + tid;
            int row = s >> 3, l = (s & 7) ^ (row & 7);
            gl_lds16(Bw + (size_t)(n0 + row) * 2048 + k0 + l * 8,
                     &Bs[(i * 256 + (tid & ~63)) * 8]);
        }
        __syncthreads();
        short8v af[4][2], bf[2][2];
        #pragma unroll
        for (int mf = 0; mf < 4; ++mf) {
            int row = wm + mf * 16 + r16;
            #pragma unroll
            for (int ksv = 0; ksv < 2; ++ksv) {
                int blk = (ksv * 4 + kb) ^ (row & 7);
                af[mf][ksv] = __builtin_bit_cast(short8v,
                    *(const ushort8v*)&As[row * 64 + blk * 8]);
            }
        }
        #pragma unroll
        for (int nf = 0; nf < 2; ++nf) {
            int row = wn + nf * 16 + r16;
            #pragma unroll
            for (int ksv = 0; ksv < 2; ++ksv) {
                int blk = (ksv * 4 + kb) ^ (row & 7);
                bf[nf][ksv] = __builtin_bit_cast(short8v,
                    *(const ushort8v*)&Bs[row * 64 + blk * 8]);
            }
        }
        #pragma unroll
        for (int mf = 0; mf < 4; ++mf)
            #pragma unroll
            for (int nf = 0; nf < 2; ++nf)
                #pragma unroll
                for (int ksv = 0; ksv < 2; ++ksv)
                    acc[mf][nf] = __builtin_amdgcn_mfma_f32_16x16x32_bf16(
                        af[mf][ksv], bf[nf][ksv], acc[mf][nf], 0, 0, 0);
        __syncthreads();
    }

    #pragma unroll
    for (int mf = 0; mf < 4; ++mf)
        #pragma unroll
        for (int nf = 0; nf < 2; ++nf)
            #pragma unroll
            for (int v = 0; v < 4; ++v) {
                int mg = m0 + wm + mf * 16 + kb * 4 + v;
                int ng = n0 + wn + nf * 16 + r16;
                int nb = ng >> 11, ngl = ng & 2047;
                u16 val = f2bf(acc[mf][nf][v]);
                if (nb == 1) {
                    size_t bh = (size_t)(mg >> 9) * 16 + (ngl >> 7);
                    kcb[(bh * 4608 + 4096 + (mg & 511)) * 128 + (ngl & 127)] = val;
                } else {
                    u16* dst = (nb == 0) ? qbf : vnb;
                    dst[(((size_t)(mg >> 9) * 16 + (ngl >> 7)) * 512 +
                         (mg & 511)) * 128 + (ngl & 127)] = val;
                }
            }
}

// ---------------------------------------------------------------------------
// fused prep_cache + QKV GEMM: grid 5632 = 512 groups x (8 prep + 3 qkv).
// 24KB LDS -> 6 blocks/CU, 24 waves/CU: prep regains TLP, qkv stalls hide
// behind co-resident blocks.
// ---------------------------------------------------------------------------
__global__ __launch_bounds__(256, 6) void fused_prep_qkv_kernel(
    const int* __restrict__ kq, const int* __restrict__ vq,
    const float* __restrict__ ks, const float* __restrict__ vs,
    u16* __restrict__ kcb, u16* __restrict__ vt,
    float* __restrict__ oktq, float* __restrict__ ovtq,
    float* __restrict__ oksc, float* __restrict__ ovsc,
    const u16* __restrict__ xb, const u16* __restrict__ wb3,
    u16* __restrict__ qbf, u16* __restrict__ vnb) {
    __shared__ __align__(16) char LB[24576];
    const int grp = blockIdx.x / 11, rem = blockIdx.x % 11;
    if (rem < 8) {
        prep_body(grp * 8 + rem, LB, kq, vq, ks, vs, kcb, vt,
                  oktq, ovtq, oksc, ovsc);
    } else {
        qkv_body(grp * 3 + (rem - 8), LB, xb, wb3, qbf, kcb, vnb);
    }
}

// ---------------------------------------------------------------------------
// W_o GEMM: C f32 row-major. (R5 known-good 4-wave dbuf version.)
// ---------------------------------------------------------------------------
__global__ __launch_bounds__(256) void gemm_wo_kernel(
    const u16* __restrict__ A, const u16* __restrict__ Bw,
    float* __restrict__ Cout) {
    __shared__ u16 As[2][128 * 64];
    __shared__ u16 Bs[2][64 * 64];
    const int tid = threadIdx.x, lane = tid & 63, w = tid >> 6;
    const int sid = (blockIdx.x & 7) * 64 + (blockIdx.x >> 3);
    const int bm = sid & 15, bn = sid >> 4;
    const int m0 = bm * 128, n0 = bn * 64;
    const int wm = (w >> 1) * 64, wn = (w & 1) * 32;
    const int r16 = lane & 15, kb = lane >> 4;

    f32x4 acc[4][2] = {};

    auto stage = [&](int bi, int k0) {
        #pragma unroll
        for (int i = 0; i < 4; ++i) {
            int s = i * 256 + tid;
            int row = s >> 3, l = (s & 7) ^ (row & 7);
            gl_lds16(A + (size_t)(m0 + row) * 2048 + k0 + l * 8,
                     &As[bi][(i * 256 + (tid & ~63)) * 8]);
        }
        #pragma unroll
        for (int i = 0; i < 2; ++i) {
            int s = i * 256 + tid;
            int row = s >> 3, l = (s & 7) ^ (row & 7);
            gl_lds16(Bw + (size_t)(n0 + row) * 2048 + k0 + l * 8,
                     &Bs[bi][(i * 256 + (tid & ~63)) * 8]);
        }
    };

    stage(0, 0);
    __syncthreads();
    int cur = 0;
    for (int t = 0; t < 32; ++t) {
        if (t < 31) stage(cur ^ 1, (t + 1) * 64);
        short8v af[4][2], bf[2][2];
        #pragma unroll
        for (int mf = 0; mf < 4; ++mf) {
            int row = wm + mf * 16 + r16;
            #pragma unroll
            for (int ksv = 0; ksv < 2; ++ksv) {
                int blk = (ksv * 4 + kb) ^ (row & 7);
                af[mf][ksv] = __builtin_bit_cast(short8v,
                    *(const ushort8v*)&As[cur][row * 64 + blk * 8]);
            }
        }
        #pragma unroll
        for (int nf = 0; nf < 2; ++nf) {
            int row = wn + nf * 16 + r16;
            #pragma unroll
            for (int ksv = 0; ksv < 2; ++ksv) {
                int blk = (ksv * 4 + kb) ^ (row & 7);
                bf[nf][ksv] = __builtin_bit_cast(short8v,
                    *(const ushort8v*)&Bs[cur][row * 64 + blk * 8]);
            }
        }
        #pragma unroll
        for (int mf = 0; mf < 4; ++mf)
            #pragma unroll
            for (int nf = 0; nf < 2; ++nf)
                #pragma unroll
                for (int ksv = 0; ksv < 2; ++ksv)
                    acc[mf][nf] = __builtin_amdgcn_mfma_f32_16x16x32_bf16(
                        af[mf][ksv], bf[nf][ksv], acc[mf][nf], 0, 0, 0);
        __syncthreads();
        cur ^= 1;
    }

    #pragma unroll
    for (int mf = 0; mf < 4; ++mf)
        #pragma unroll
        for (int nf = 0; nf < 2; ++nf)
            #pragma unroll
            for (int v = 0; v < 4; ++v) {
                int mg = m0 + wm + mf * 16 + kb * 4 + v;
                int ng = n0 + wn + nf * 16 + r16;
                Cout[(size_t)mg * 2048 + ng] = acc[mf][nf][v];
            }
}

// ---------------------------------------------------------------------------
// quant_new: quantize new K/V rows + V^T cols 4096..4607. Grid 512, 256 thr.
// ---------------------------------------------------------------------------
__global__ __launch_bounds__(256) void quant_new_kernel(
    const u16* __restrict__ kcb, const u16* __restrict__ vnb,
    u16* __restrict__ vt,
    float* __restrict__ oktq, float* __restrict__ ovtq,
    float* __restrict__ oksc, float* __restrict__ ovsc) {
    __shared__ u16 Vs[64][132];
    const int tid = threadIdx.x;
    const int bh = blockIdx.x >> 3, kt = blockIdx.x & 7;
    const int i0 = kt << 6;
    const int lane = tid & 63, w = tid >> 6;
    const int q31 = lane & 31, rh = lane >> 5;
    #pragma unroll 4
    for (int s = 0; s < 8; ++s) {
        const int key = s * 8 + w * 2 + rh;
        const int i = i0 + key;
        u32x2v ku = *(const u32x2v*)(kcb + ((size_t)bh * 4608 + 4096 + i) * 128 + q31 * 4);
        u32x2v vu = *(const u32x2v*)(vnb + ((size_t)bh * 512 + i) * 128 + q31 * 4);
        f32x4 kx, vx;
        kx[0] = bf2f((u16)ku[0]); kx[1] = bf2f((u16)(ku[0] >> 16));
        kx[2] = bf2f((u16)ku[1]); kx[3] = bf2f((u16)(ku[1] >> 16));
        vx[0] = bf2f((u16)vu[0]); vx[1] = bf2f((u16)(vu[0] >> 16));
        vx[2] = bf2f((u16)vu[1]); vx[3] = bf2f((u16)(vu[1] >> 16));
        *(u32x2v*)&Vs[key][q31 * 4] = vu;
        float kam = fmaxf(fmaxf(fabsf(kx[0]), fabsf(kx[1])), fmaxf(fabsf(kx[2]), fabsf(kx[3])));
        float vam = fmaxf(fmaxf(fabsf(vx[0]), fabsf(vx[1])), fmaxf(fabsf(vx[2]), fabsf(vx[3])));
        #pragma unroll
        for (int off = 1; off < 32; off <<= 1) {
            kam = fmaxf(kam, __shfl_xor(kam, off, 64));
            vam = fmaxf(vam, __shfl_xor(vam, off, 64));
        }
        float kscale = fmaxf(kam / 127.0f, 1e-8f);
        float vscale = fmaxf(vam / 127.0f, 1e-8f);
        float kinv = 1.0f / kscale, vinv = 1.0f / vscale;
        const size_t orow = (size_t)bh * 4096 + 3584 + i;
        f32x4 ko, vo;
        #pragma unroll
        for (int e = 0; e < 4; ++e) {
            ko[e] = fminf(fmaxf(rintf(kx[e] * kinv), -127.f), 127.f);
            vo[e] = fminf(fmaxf(rintf(vx[e] * vinv), -127.f), 127.f);
        }
        *(f32x4*)(oktq + orow * 128 + q31 * 4) = ko;
        *(f32x4*)(ovtq + orow * 128 + q31 * 4) = vo;
        if (q31 == 0) {
            oksc[orow] = __half2float(__float2half(kscale));
            ovsc[orow] = __half2float(__float2half(vscale));
        }
    }
    __syncthreads();
    const int d = tid >> 1, half = tid & 1;
    u16* obase = vt + ((size_t)bh * 128 + d) * 4608 + 4096 + i0 + half * 32;
    #pragma unroll
    for (int c = 0; c < 4; ++c) {
        ushort8v tv;
        #pragma unroll
        for (int e = 0; e < 8; ++e) tv[e] = Vs[half * 32 + c * 8 + e][d];
        *(ushort8v*)(obase + c * 8) = tv;
    }
}

// ---------------------------------------------------------------------------
// attn split-K: 768 blocks = 64 bh x 4 q-tiles(128) x 3 key-splits.
// KVBLK=32, LDS 32KB -> 3 blocks/CU = 12 waves/CU. 4 waves x 32 q-rows;
// 32x32x16 MFMA; swapped QK^T; in-register softmax; cvt_pk+permlane.
// ---------------------------------------------------------------------------
__global__ __launch_bounds__(256, 3) void attn_kernel(
    const u16* __restrict__ qb, const u16* __restrict__ kcb,
    const u16* __restrict__ vt,
    u16* __restrict__ Op0, u16* __restrict__ Op1, u16* __restrict__ Op2,
    float* __restrict__ mlp) {
    __shared__ u16 Ks[2][32 * 128];
    __shared__ u16 Vl[2][128 * 32];

    const int tid = threadIdx.x, lane = tid & 63, w = tid >> 6;
    const int p = blockIdx.x;
    const int xcd = p & 7, i = p >> 3;
    const int qt2 = i & 3, spw = (i >> 2) % 3;
    const int bh = ((i / 12) << 3) | xcd;      // bh%8 == xcd
    const int q31 = lane & 31, hi = lane >> 5;
    const int qrow = qt2 * 128 + w * 32 + q31;

    const u16* qp = qb + ((size_t)bh * 512 + qrow) * 128 + hi * 8;
    short8v qf[8];
    #pragma unroll
    for (int s = 0; s < 8; ++s)
        qf[s] = __builtin_bit_cast(short8v, *(const ushort8v*)(qp + s * 16));

    f32x16 O[4] = {};
    float m_i = -3.0e38f, l_i = 0.f;

    const size_t kbase = (size_t)bh * 4608 * 128;
    const size_t vbase = (size_t)bh * 128 * 4608;
    const int e = 132 + 4 * qt2;               // total 32-key tiles
    const int ktA = (e * spw) / 3;
    const int ktB = (e * (spw + 1)) / 3;

    auto STAGE = [&](int bi, int kt) {
        #pragma unroll
        for (int ii = 0; ii < 2; ++ii) {
            int s = ii * 256 + tid;
            int row = s >> 4, l = (s & 15) ^ (row & 7);
            gl_lds16(kcb + kbase + (size_t)(kt * 32 + row) * 128 + l * 8,
                     &Ks[bi][(ii * 256 + (tid & ~63)) * 8]);
        }
        #pragma unroll
        for (int ii = 0; ii < 2; ++ii) {
            int s = ii * 256 + tid;
            int row = s >> 2, l = (s & 3) ^ (row & 3);
            gl_lds16(vt + vbase + (size_t)row * 4608 + kt * 32 + l * 8,
                     &Vl[bi][(ii * 256 + (tid & ~63)) * 8]);
        }
    };

    STAGE(0, ktA);
    __syncthreads();
    int cur = 0;
    for (int kt = ktA; kt < ktB; ++kt) {
        if (kt + 1 < ktB) STAGE(cur ^ 1, kt + 1);

        f32x16 S = {};
        __builtin_amdgcn_s_setprio(1);
        #pragma unroll
        for (int s = 0; s < 8; ++s) {
            int blk = (2 * s + hi) ^ (q31 & 7);
            short8v kf = __builtin_bit_cast(short8v,
                *(const ushort8v*)&Ks[cur][q31 * 128 + blk * 8]);
            S = __builtin_amdgcn_mfma_f32_32x32x16_bf16(kf, qf[s], S, 0, 0, 0);
        }
        __builtin_amdgcn_s_setprio(0);

        if (kt >= 128) {  // causal mask within the new segment
            const int kb0 = (kt - 128) * 32 + 4 * hi;
            #pragma unroll
            for (int r = 0; r < 16; ++r) {
                int koff = kb0 + (r & 3) + 8 * (r >> 2);
                if (koff > qrow) S[r] = -3.0e38f;
            }
        }

        float mx = S[0];
        #pragma unroll
        for (int r = 1; r < 16; ++r) mx = fmaxf(mx, S[r]);
        mx = fmaxf(mx, __shfl_xor(mx, 32, 64));

        if (__ballot(mx > m_i + 8.f)) {
            float mnew = fmaxf(m_i, mx);
            float alpha = __expf(m_i - mnew);
            m_i = mnew;
            l_i *= alpha;
            #pragma unroll
            for (int r = 0; r < 16; ++r) {
                float ar = __shfl(alpha, (r & 3) + 8 * (r >> 2) + 4 * hi, 64);
                O[0][r] *= ar; O[1][r] *= ar; O[2][r] *= ar; O[3][r] *= ar;
            }
        }
        #pragma unroll
        for (int r = 0; r < 16; ++r) {
            S[r] = __expf(S[r] - m_i); l_i += S[r];
        }

        __builtin_amdgcn_s_setprio(1);
        #pragma unroll
        for (int j = 0; j < 2; ++j) {
            const int r0 = 8 * j;
            u32 a0, a1, b0, b1;
            asm("v_cvt_pk_bf16_f32 %0, %1, %2" : "=v"(a0) : "v"(S[r0+0]), "v"(S[r0+1]));
            asm("v_cvt_pk_bf16_f32 %0, %1, %2" : "=v"(a1) : "v"(S[r0+2]), "v"(S[r0+3]));
            asm("v_cvt_pk_bf16_f32 %0, %1, %2" : "=v"(b0) : "v"(S[r0+4]), "v"(S[r0+5]));
            asm("v_cvt_pk_bf16_f32 %0, %1, %2" : "=v"(b1) : "v"(S[r0+6]), "v"(S[r0+7]));
            asm("v_permlane32_swap_b32 %0, %1" : "+v"(a0), "+v"(b0));
            asm("v_permlane32_swap_b32 %0, %1" : "+v"(a1), "+v"(b1));
            u32x4v pw = {a0, a1, b0, b1};
            short8v pf = __builtin_bit_cast(short8v, pw);
            #pragma unroll
            for (int od = 0; od < 4; ++od) {
                int vrow = od * 32 + q31;
                int blk = (2 * j + hi) ^ (vrow & 3);
                short8v vf = __builtin_bit_cast(short8v,
                    *(const ushort8v*)&Vl[cur][vrow * 32 + blk * 8]);
                O[od] = __builtin_amdgcn_mfma_f32_32x32x16_bf16(pf, vf, O[od], 0, 0, 0);
            }
        }
        __builtin_amdgcn_s_setprio(0);

        __syncthreads();
        cur ^= 1;
    }

    // partial epilogue: unnormalized O (bf16) + (m, l)
    float lt = l_i + __shfl_xor(l_i, 32, 64);
    u16* Op = (spw == 0) ? Op0 : ((spw == 1) ? Op1 : Op2);
    const size_t pbase = ((size_t)bh * 4 + qt2) * 16384;
    #pragma unroll
    for (int r = 0; r < 16; ++r) {
        int qoff = (r & 3) + 8 * (r >> 2) + 4 * hi;
        size_t rowb = pbase + (size_t)(w * 32 + qoff) * 128 + q31;
        Op[rowb +  0] = f2bf(O[0][r]);
        Op[rowb + 32] = f2bf(O[1][r]);
        Op[rowb + 64] = f2bf(O[2][r]);
        Op[rowb + 96] = f2bf(O[3][r]);
    }
    if (hi == 0) {
        int qg = ((spw * 256 + bh * 4 + qt2) * 128 + w * 32 + q31);
        mlp[qg * 2 + 0] = m_i;
        mlp[qg * 2 + 1] = lt;
    }
}

// ---------------------------------------------------------------------------
// combine (blocks 0..255) + Wo convert (blocks 256..2303) in one dispatch:
// independent works, removes a serial launch.
// ---------------------------------------------------------------------------
__global__ __launch_bounds__(256) void combine_conv_kernel(
    const u16* __restrict__ Op0, const u16* __restrict__ Op1,
    const u16* __restrict__ Op2,
    const float* __restrict__ mlp, u16* __restrict__ yb,
    const float* __restrict__ Wo, u16* __restrict__ wb3) {
    if (blockIdx.x >= 256) {
        const int idx = (blockIdx.x - 256) * 256 + threadIdx.x;
        const float* p = Wo + (size_t)idx * 8;
        f32x4 a = *(const f32x4*)p, b = *(const f32x4*)(p + 4);
        ushort8v o;
        o[0]=f2bf(a[0]); o[1]=f2bf(a[1]); o[2]=f2bf(a[2]); o[3]=f2bf(a[3]);
        o[4]=f2bf(b[0]); o[5]=f2bf(b[1]); o[6]=f2bf(b[2]); o[7]=f2bf(b[3]);
        *(ushort8v*)(wb3 + (size_t)idx * 8) = o;
        return;
    }
    const int p = blockIdx.x;
    const int bh = p >> 2, qt2 = p & 3;
    const int b = bh >> 4, h = bh & 15;
    const int q = threadIdx.x >> 1, dh = threadIdx.x & 1;
    const int base = (bh * 4 + qt2) * 128 + q;
    float m0 = mlp[base * 2],               l0 = mlp[base * 2 + 1];
    float m1 = mlp[(32768 + base) * 2],     l1 = mlp[(32768 + base) * 2 + 1];
    float m2 = mlp[(65536 + base) * 2],     l2 = mlp[(65536 + base) * 2 + 1];
    float M = fmaxf(fmaxf(m0, m1), m2);
    float a0 = __expf(m0 - M), a1 = __expf(m1 - M), a2 = __expf(m2 - M);
    float invL = 1.0f / (l0 * a0 + l1 * a1 + l2 * a2);
    a0 *= invL; a1 *= invL; a2 *= invL;
    const size_t pb = ((size_t)bh * 4 + qt2) * 16384 + (size_t)q * 128 + dh * 64;
    u16* dst = yb + ((size_t)(b * 512 + qt2 * 128 + q)) * 2048 + h * 128 + dh * 64;
    #pragma unroll
    for (int j = 0; j < 8; ++j) {
        ushort8v o0 = *(const ushort8v*)(Op0 + pb + j * 8);
        ushort8v o1 = *(const ushort8v*)(Op1 + pb + j * 8);
        ushort8v o2 = *(const ushort8v*)(Op2 + pb + j * 8);
        ushort8v o;
        #pragma unroll
        for (int e = 0; e < 8; ++e)
            o[e] = f2bf(bf2f(o0[e]) * a0 + bf2f(o1[e]) * a1 + bf2f(o2[e]) * a2);
        *(ushort8v*)(dst + j * 8) = o;
    }
}

// ---------------------------------------------------------------------------
extern "C" void kernel_launch(void* const* d_in, const int* in_sizes, int n_in,
                              void* d_out, int out_size, void* d_ws, size_t ws_size,
                              hipStream_t stream) {
    (void)in_sizes; (void)n_in; (void)out_size; (void)ws_size;
    const float* x   = (const float*)d_in[0];
    const int*   kq  = (const int*)d_in[1];
    const int*   vq  = (const int*)d_in[2];
    const float* ks  = (const float*)d_in[3];
    const float* vs  = (const float*)d_in[4];
    const float* Wq  = (const float*)d_in[5];
    const float* Wk  = (const float*)d_in[6];
    const float* Wv  = (const float*)d_in[7];
    const float* Wo  = (const float*)d_in[8];

    float* out  = (float*)d_out;
    float* y_o  = out;
    float* oktq = out + 4194304;
    float* ovtq = out + 37748736;
    float* oksc = out + 71303168;
    float* ovsc = out + 71565312;
    float* mlp  = out;   // y region is free until the final GEMM

    char* wsb = (char*)d_ws;
    u16* kcb = (u16*)(wsb);                       // 75.5 MB: [64][4608][128]
    u16* vtb = (u16*)(wsb + 75497472);            // 75.5 MB: [64][128][4608]
    u16* xb  = (u16*)(wsb + 150994944);           // 8 MB; later Opart split-0
    u16* qbf = (u16*)(wsb + 159383552);           // 8 MB; later combine output
    u16* vnb = (u16*)(wsb + 167772160);           // 8 MB; later Opart split-1
    u16* ybf = (u16*)(wsb + 176160768);           // 8 MB; later Opart split-2
    u16* wb3 = (u16*)(wsb + 184549376);           // 24 MB: [Wq*s; Wk; Wv] bf16

    const float rscale = 0.08838834764831845f;    // 1/sqrt(128)

    convert4_kernel<<<8192, 256, 0, stream>>>(x, Wq, Wk, Wv, xb, wb3, rscale);
    fused_prep_qkv_kernel<<<5632, 256, 0, stream>>>(
        kq, vq, ks, vs, kcb, vtb, oktq, ovtq, oksc, ovsc,
        xb, wb3, qbf, vnb);
    quant_new_kernel<<<512, 256, 0, stream>>>(kcb, vnb, vtb,
                                              oktq, ovtq, oksc, ovsc);
    attn_kernel<<<768, 256, 0, stream>>>(qbf, kcb, vtb, xb, vnb, ybf, mlp);
    combine_conv_kernel<<<2304, 256, 0, stream>>>(xb, vnb, ybf, mlp, qbf,
                                                  Wo, wb3);
    gemm_wo_kernel<<<512, 256, 0, stream>>>(qbf, wb3, y_o);
}

// Round 15
// 401.146 us; speedup vs baseline: 1.1360x; 1.1360x over previous
//
#include <hip/hip_runtime.h>
#include <hip/hip_fp16.h>

typedef float   f32x4   __attribute__((ext_vector_type(4)));
typedef float   f32x2   __attribute__((ext_vector_type(2)));
typedef float   f32x16  __attribute__((ext_vector_type(16)));
typedef short   short8v __attribute__((ext_vector_type(8)));
typedef unsigned short ushort8v __attribute__((ext_vector_type(8)));
typedef unsigned int   u32x4v __attribute__((ext_vector_type(4)));
typedef unsigned int   u32x2v __attribute__((ext_vector_type(2)));
typedef int     int4v   __attribute__((ext_vector_type(4)));
typedef unsigned int   u32;
typedef unsigned short u16;

#define DEVI static __device__ __forceinline__

DEVI u16 f2bf(float f) {
    u32 u = __builtin_bit_cast(u32, f);
    u += 0x7FFFu + ((u >> 16) & 1u);   // RNE (inputs finite)
    return (u16)(u >> 16);
}
DEVI float bf2f(u16 h) { return __builtin_bit_cast(float, (u32)h << 16); }

// async global->LDS, 16B per lane; lds ptr must be wave-uniform (lane*16 added by HW)
DEVI void gl_lds16(const u16* g, u16* l) {
    __builtin_amdgcn_global_load_lds(
        (const __attribute__((address_space(1))) u32*)(const void*)g,
        (__attribute__((address_space(3))) u32*)(void*)l, 16, 0, 0);
}

// ---------------------------------------------------------------------------
// fused convert of 4 matrices: x->xb, Wq*rscale->wb3, Wk->wb3+4M, Wv->wb3+8M.
// Grid 8192 = 4 segs x 2048 blocks.
// ---------------------------------------------------------------------------
__global__ __launch_bounds__(256) void convert4_kernel(
    const float* __restrict__ x, const float* __restrict__ Wq,
    const float* __restrict__ Wk, const float* __restrict__ Wv,
    u16* __restrict__ xb, u16* __restrict__ wb3, float rscale) {
    const int seg = blockIdx.x >> 11;
    const int idx = (blockIdx.x & 2047) * 256 + threadIdx.x;
    const float* src; u16* dst; float scale = 1.0f;
    if (seg == 0)      { src = x;  dst = xb; }
    else if (seg == 1) { src = Wq; dst = wb3; scale = rscale; }
    else if (seg == 2) { src = Wk; dst = wb3 + 4194304; }
    else               { src = Wv; dst = wb3 + 8388608; }
    const float* p = src + (size_t)idx * 8;
    f32x4 a = *(const f32x4*)p, b = *(const f32x4*)(p + 4);
    ushort8v o;
    o[0]=f2bf(a[0]*scale); o[1]=f2bf(a[1]*scale); o[2]=f2bf(a[2]*scale); o[3]=f2bf(a[3]*scale);
    o[4]=f2bf(b[0]*scale); o[5]=f2bf(b[1]*scale); o[6]=f2bf(b[2]*scale); o[7]=f2bf(b[3]*scale);
    *(ushort8v*)(dst + (size_t)idx * 8) = o;
}

// ---------------------------------------------------------------------------
// prep_cache: dequant cache -> bf16 K rows (kcb rows 0..4095) + bf16 V^T cols
// 0..4095 + exact requant of window rows 512..4095. Grid 4096, 256 thr.
// (R9 known-best version: 2 rows/wave, 16B loads, 17KB LDS, ~70% occupancy.)
// ---------------------------------------------------------------------------
__global__ __launch_bounds__(256) void prep_cache_kernel(
    const int* __restrict__ kq, const int* __restrict__ vq,
    const float* __restrict__ ks, const float* __restrict__ vs,
    u16* __restrict__ kcb, u16* __restrict__ vt,
    float* __restrict__ oktq, float* __restrict__ ovtq,
    float* __restrict__ oksc, float* __restrict__ ovsc) {
    __shared__ u16 Vs[64][132];
    __shared__ float skL[64], svL[64];
    const int tid = threadIdx.x;
    const int bh = blockIdx.x >> 6, kt = blockIdx.x & 63;
    const int key0 = kt << 6;
    const size_t rowbase = (size_t)bh * 4096 + key0;
    if (tid < 64) { skL[tid] = ks[rowbase + tid]; svL[tid] = vs[rowbase + tid]; }
    __syncthreads();
    const int lane = tid & 63, w = tid >> 6;
    const int q31 = lane & 31, rh = lane >> 5;
    u32x2v* kcw = (u32x2v*)kcb;
    #pragma unroll 4
    for (int s = 0; s < 8; ++s) {
        const int key = s * 8 + w * 2 + rh;
        const size_t row = rowbase + key;
        const float sk = skL[key], sv = svL[key];
        int4v kv = *(const int4v*)(kq + row * 128 + q31 * 4);
        int4v vv = *(const int4v*)(vq + row * 128 + q31 * 4);
        f32x4 kx, vx;
        #pragma unroll
        for (int e = 0; e < 4; ++e) { kx[e] = (float)kv[e] * sk; vx[e] = (float)vv[e] * sv; }
        u32x2v kp, vp;
        kp[0] = (u32)f2bf(kx[0]) | ((u32)f2bf(kx[1]) << 16);
        kp[1] = (u32)f2bf(kx[2]) | ((u32)f2bf(kx[3]) << 16);
        vp[0] = (u32)f2bf(vx[0]) | ((u32)f2bf(vx[1]) << 16);
        vp[1] = (u32)f2bf(vx[2]) | ((u32)f2bf(vx[3]) << 16);
        kcw[(size_t)(bh * 4608 + key0 + key) * 32 + q31] = kp;
        *(u32x2v*)&Vs[key][q31 * 4] = vp;
        float kam = fmaxf(fmaxf(fabsf(kx[0]), fabsf(kx[1])), fmaxf(fabsf(kx[2]), fabsf(kx[3])));
        float vam = fmaxf(fmaxf(fabsf(vx[0]), fabsf(vx[1])), fmaxf(fabsf(vx[2]), fabsf(vx[3])));
        #pragma unroll
        for (int off = 1; off < 32; off <<= 1) {
            kam = fmaxf(kam, __shfl_xor(kam, off, 64));
            vam = fmaxf(vam, __shfl_xor(vam, off, 64));
        }
        const int r = key0 + key;
        if (r >= 512) {
            const size_t orow = (size_t)bh * 4096 + (size_t)(r - 512);
            float kscale = fmaxf(kam / 127.0f, 1e-8f);
            float vscale = fmaxf(vam / 127.0f, 1e-8f);
            float kinv = 1.0f / kscale, vinv = 1.0f / vscale;
            f32x4 ko, vo;
            #pragma unroll
            for (int e = 0; e < 4; ++e) {
                ko[e] = fminf(fmaxf(rintf(kx[e] * kinv), -127.f), 127.f);
                vo[e] = fminf(fmaxf(rintf(vx[e] * vinv), -127.f), 127.f);
            }
            *(f32x4*)(oktq + orow * 128 + q31 * 4) = ko;
            *(f32x4*)(ovtq + orow * 128 + q31 * 4) = vo;
            if (q31 == 0) {
                oksc[orow] = __half2float(__float2half(kscale));
                ovsc[orow] = __half2float(__float2half(vscale));
            }
        }
    }
    __syncthreads();
    const int d = tid >> 1, half = tid & 1;
    u16* obase = vt + ((size_t)bh * 128 + d) * 4608 + key0 + half * 32;
    #pragma unroll
    for (int c = 0; c < 4; ++c) {
        ushort8v tv;
        #pragma unroll
        for (int e = 0; e < 8; ++e) tv[e] = Vs[half * 32 + c * 8 + e][d];
        *(ushort8v*)(obase + c * 8) = tv;
    }
}

// ---------------------------------------------------------------------------
// fused QKV GEMM: C[m][n] = sum_k A[m][k]*W3[n][k], M=K=2048, N=6144.
// Grid 1536, 256 thr (4 waves 2x2 of 64x32), BM=128 BN=64 BK=64, dbuf.
// (R9 known-best version.)
// ---------------------------------------------------------------------------
__global__ __launch_bounds__(256) void gemm_qkv_kernel(
    const u16* __restrict__ A, const u16* __restrict__ Bw,
    u16* __restrict__ qbf, u16* __restrict__ kcb, u16* __restrict__ vnb) {
    __shared__ u16 As[2][128 * 64];
    __shared__ u16 Bs[2][64 * 64];
    const int tid = threadIdx.x, lane = tid & 63, w = tid >> 6;
    const int sid = (blockIdx.x & 7) * 192 + (blockIdx.x >> 3);  // XCD-chunked
    const int bm = sid & 15, bn = sid >> 4;
    const int m0 = bm * 128, n0 = bn * 64;
    const int wm = (w >> 1) * 64, wn = (w & 1) * 32;
    const int r16 = lane & 15, kb = lane >> 4;

    f32x4 acc[4][2] = {};

    auto stage = [&](int bi, int k0) {
        #pragma unroll
        for (int i = 0; i < 4; ++i) {
            int s = i * 256 + tid;
            int row = s >> 3, l = (s & 7) ^ (row & 7);
            gl_lds16(A + (size_t)(m0 + row) * 2048 + k0 + l * 8,
                     &As[bi][(i * 256 + (tid & ~63)) * 8]);
        }
        #pragma unroll
        for (int i = 0; i < 2; ++i) {
            int s = i * 256 + tid;
            int row = s >> 3, l = (s & 7) ^ (row & 7);
            gl_lds16(Bw + (size_t)(n0 + row) * 2048 + k0 + l * 8,
                     &Bs[bi][(i * 256 + (tid & ~63)) * 8]);
        }
    };

    stage(0, 0);
    __syncthreads();
    int cur = 0;
    for (int t = 0; t < 32; ++t) {
        if (t < 31) stage(cur ^ 1, (t + 1) * 64);
        short8v af[4][2], bf[2][2];
        #pragma unroll
        for (int mf = 0; mf < 4; ++mf) {
            int row = wm + mf * 16 + r16;
            #pragma unroll
            for (int ksv = 0; ksv < 2; ++ksv) {
                int blk = (ksv * 4 + kb) ^ (row & 7);
                af[mf][ksv] = __builtin_bit_cast(short8v,
                    *(const ushort8v*)&As[cur][row * 64 + blk * 8]);
            }
        }
        #pragma unroll
        for (int nf = 0; nf < 2; ++nf) {
            int row = wn + nf * 16 + r16;
            #pragma unroll
            for (int ksv = 0; ksv < 2; ++ksv) {
                int blk = (ksv * 4 + kb) ^ (row & 7);
                bf[nf][ksv] = __builtin_bit_cast(short8v,
                    *(const ushort8v*)&Bs[cur][row * 64 + blk * 8]);
            }
        }
        #pragma unroll
        for (int mf = 0; mf < 4; ++mf)
            #pragma unroll
            for (int nf = 0; nf < 2; ++nf)
                #pragma unroll
                for (int ksv = 0; ksv < 2; ++ksv)
                    acc[mf][nf] = __builtin_amdgcn_mfma_f32_16x16x32_bf16(
                        af[mf][ksv], bf[nf][ksv], acc[mf][nf], 0, 0, 0);
        __syncthreads();
        cur ^= 1;
    }

    #pragma unroll
    for (int mf = 0; mf < 4; ++mf)
        #pragma unroll
        for (int nf = 0; nf < 2; ++nf)
            #pragma unroll
            for (int v = 0; v < 4; ++v) {
                int mg = m0 + wm + mf * 16 + kb * 4 + v;
                int ng = n0 + wn + nf * 16 + r16;
                int nb = ng >> 11, ngl = ng & 2047;
                u16 val = f2bf(acc[mf][nf][v]);
                if (nb == 1) {
                    size_t bh = (size_t)(mg >> 9) * 16 + (ngl >> 7);
                    kcb[(bh * 4608 + 4096 + (mg & 511)) * 128 + (ngl & 127)] = val;
                } else {
                    u16* dst = (nb == 0) ? qbf : vnb;
                    dst[(((size_t)(mg >> 9) * 16 + (ngl >> 7)) * 512 +
                         (mg & 511)) * 128 + (ngl & 127)] = val;
                }
            }
}

// ---------------------------------------------------------------------------
// W_o GEMM: C f32 row-major. (R5 known-good 4-wave dbuf version.)
// ---------------------------------------------------------------------------
__global__ __launch_bounds__(256) void gemm_wo_kernel(
    const u16* __restrict__ A, const u16* __restrict__ Bw,
    float* __restrict__ Cout) {
    __shared__ u16 As[2][128 * 64];
    __shared__ u16 Bs[2][64 * 64];
    const int tid = threadIdx.x, lane = tid & 63, w = tid >> 6;
    const int sid = (blockIdx.x & 7) * 64 + (blockIdx.x >> 3);
    const int bm = sid & 15, bn = sid >> 4;
    const int m0 = bm * 128, n0 = bn * 64;
    const int wm = (w >> 1) * 64, wn = (w & 1) * 32;
    const int r16 = lane & 15, kb = lane >> 4;

    f32x4 acc[4][2] = {};

    auto stage = [&](int bi, int k0) {
        #pragma unroll
        for (int i = 0; i < 4; ++i) {
            int s = i * 256 + tid;
            int row = s >> 3, l = (s & 7) ^ (row & 7);
            gl_lds16(A + (size_t)(m0 + row) * 2048 + k0 + l * 8,
                     &As[bi][(i * 256 + (tid & ~63)) * 8]);
        }
        #pragma unroll
        for (int i = 0; i < 2; ++i) {
            int s = i * 256 + tid;
            int row = s >> 3, l = (s & 7) ^ (row & 7);
            gl_lds16(Bw + (size_t)(n0 + row) * 2048 + k0 + l * 8,
                     &Bs[bi][(i * 256 + (tid & ~63)) * 8]);
        }
    };

    stage(0, 0);
    __syncthreads();
    int cur = 0;
    for (int t = 0; t < 32; ++t) {
        if (t < 31) stage(cur ^ 1, (t + 1) * 64);
        short8v af[4][2], bf[2][2];
        #pragma unroll
        for (int mf = 0; mf < 4; ++mf) {
            int row = wm + mf * 16 + r16;
            #pragma unroll
            for (int ksv = 0; ksv < 2; ++ksv) {
                int blk = (ksv * 4 + kb) ^ (row & 7);
                af[mf][ksv] = __builtin_bit_cast(short8v,
                    *(const ushort8v*)&As[cur][row * 64 + blk * 8]);
            }
        }
        #pragma unroll
        for (int nf = 0; nf < 2; ++nf) {
            int row = wn + nf * 16 + r16;
            #pragma unroll
            for (int ksv = 0; ksv < 2; ++ksv) {
                int blk = (ksv * 4 + kb) ^ (row & 7);
                bf[nf][ksv] = __builtin_bit_cast(short8v,
                    *(const ushort8v*)&Bs[cur][row * 64 + blk * 8]);
            }
        }
        #pragma unroll
        for (int mf = 0; mf < 4; ++mf)
            #pragma unroll
            for (int nf = 0; nf < 2; ++nf)
                #pragma unroll
                for (int ksv = 0; ksv < 2; ++ksv)
                    acc[mf][nf] = __builtin_amdgcn_mfma_f32_16x16x32_bf16(
                        af[mf][ksv], bf[nf][ksv], acc[mf][nf], 0, 0, 0);
        __syncthreads();
        cur ^= 1;
    }

    #pragma unroll
    for (int mf = 0; mf < 4; ++mf)
        #pragma unroll
        for (int nf = 0; nf < 2; ++nf)
            #pragma unroll
            for (int v = 0; v < 4; ++v) {
                int mg = m0 + wm + mf * 16 + kb * 4 + v;
                int ng = n0 + wn + nf * 16 + r16;
                Cout[(size_t)mg * 2048 + ng] = acc[mf][nf][v];
            }
}

// ---------------------------------------------------------------------------
// quant_new: quantize new K/V rows + V^T cols 4096..4607. Grid 512, 256 thr.
// (R9 known-best version.)
// ---------------------------------------------------------------------------
__global__ __launch_bounds__(256) void quant_new_kernel(
    const u16* __restrict__ kcb, const u16* __restrict__ vnb,
    u16* __restrict__ vt,
    float* __restrict__ oktq, float* __restrict__ ovtq,
    float* __restrict__ oksc, float* __restrict__ ovsc) {
    __shared__ u16 Vs[64][132];
    const int tid = threadIdx.x;
    const int bh = blockIdx.x >> 3, kt = blockIdx.x & 7;
    const int i0 = kt << 6;
    const int lane = tid & 63, w = tid >> 6;
    const int q31 = lane & 31, rh = lane >> 5;
    #pragma unroll 4
    for (int s = 0; s < 8; ++s) {
        const int key = s * 8 + w * 2 + rh;
        const int i = i0 + key;
        u32x2v ku = *(const u32x2v*)(kcb + ((size_t)bh * 4608 + 4096 + i) * 128 + q31 * 4);
        u32x2v vu = *(const u32x2v*)(vnb + ((size_t)bh * 512 + i) * 128 + q31 * 4);
        f32x4 kx, vx;
        kx[0] = bf2f((u16)ku[0]); kx[1] = bf2f((u16)(ku[0] >> 16));
        kx[2] = bf2f((u16)ku[1]); kx[3] = bf2f((u16)(ku[1] >> 16));
        vx[0] = bf2f((u16)vu[0]); vx[1] = bf2f((u16)(vu[0] >> 16));
        vx[2] = bf2f((u16)vu[1]); vx[3] = bf2f((u16)(vu[1] >> 16));
        *(u32x2v*)&Vs[key][q31 * 4] = vu;
        float kam = fmaxf(fmaxf(fabsf(kx[0]), fabsf(kx[1])), fmaxf(fabsf(kx[2]), fabsf(kx[3])));
        float vam = fmaxf(fmaxf(fabsf(vx[0]), fabsf(vx[1])), fmaxf(fabsf(vx[2]), fabsf(vx[3])));
        #pragma unroll
        for (int off = 1; off < 32; off <<= 1) {
            kam = fmaxf(kam, __shfl_xor(kam, off, 64));
            vam = fmaxf(vam, __shfl_xor(vam, off, 64));
        }
        float kscale = fmaxf(kam / 127.0f, 1e-8f);
        float vscale = fmaxf(vam / 127.0f, 1e-8f);
        float kinv = 1.0f / kscale, vinv = 1.0f / vscale;
        const size_t orow = (size_t)bh * 4096 + 3584 + i;
        f32x4 ko, vo;
        #pragma unroll
        for (int e = 0; e < 4; ++e) {
            ko[e] = fminf(fmaxf(rintf(kx[e] * kinv), -127.f), 127.f);
            vo[e] = fminf(fmaxf(rintf(vx[e] * vinv), -127.f), 127.f);
        }
        *(f32x4*)(oktq + orow * 128 + q31 * 4) = ko;
        *(f32x4*)(ovtq + orow * 128 + q31 * 4) = vo;
        if (q31 == 0) {
            oksc[orow] = __half2float(__float2half(kscale));
            ovsc[orow] = __half2float(__float2half(vscale));
        }
    }
    __syncthreads();
    const int d = tid >> 1, half = tid & 1;
    u16* obase = vt + ((size_t)bh * 128 + d) * 4608 + 4096 + i0 + half * 32;
    #pragma unroll
    for (int c = 0; c < 4; ++c) {
        ushort8v tv;
        #pragma unroll
        for (int e = 0; e < 8; ++e) tv[e] = Vs[half * 32 + c * 8 + e][d];
        *(ushort8v*)(obase + c * 8) = tv;
    }
}

// ---------------------------------------------------------------------------
// attn split-K: 512 blocks = 64 bh x 4 q-tiles(128) x 2 key-splits.
// 4 waves x 32 q-rows; 32x32x16 MFMA; swapped QK^T; in-register softmax;
// cvt_pk+permlane P fragments; partial (m,l,O bf16) out. 8 waves/CU.
// (R9 known-best version.)
// ---------------------------------------------------------------------------
__global__ __launch_bounds__(256, 2) void attn_kernel(
    const u16* __restrict__ qb, const u16* __restrict__ kcb,
    const u16* __restrict__ vt, u16* __restrict__ Op0, u16* __restrict__ Op1,
    float* __restrict__ mlp) {
    __shared__ u16 Ks[2][64 * 128];
    __shared__ u16 Vl[2][128 * 64];

    const int tid = threadIdx.x, lane = tid & 63, w = tid >> 6;
    const int p = blockIdx.x;
    const int xcd = p & 7, i = p >> 3;
    const int qt2 = i & 3, sp = (i >> 2) & 1;
    const int bh = ((i >> 3) << 3) | xcd;      // bh%8 == xcd
    const int q31 = lane & 31, hi = lane >> 5;
    const int qrow = qt2 * 128 + w * 32 + q31;

    const u16* qp = qb + ((size_t)bh * 512 + qrow) * 128 + hi * 8;
    short8v qf[8];
    #pragma unroll
    for (int s = 0; s < 8; ++s)
        qf[s] = __builtin_bit_cast(short8v, *(const ushort8v*)(qp + s * 16));

    f32x16 O[4] = {};
    float m_i = -3.0e38f, l_i = 0.f;

    const size_t kbase = (size_t)bh * 4608 * 128;
    const size_t vbase = (size_t)bh * 128 * 4608;
    const int ktA = sp ? 32 : 0;
    const int ktB = sp ? (66 + 2 * qt2) : 32;

    auto STAGE = [&](int bi, int kt) {
        #pragma unroll
        for (int ii = 0; ii < 4; ++ii) {
            int s = ii * 256 + tid;
            int row = s >> 4, l = (s & 15) ^ (row & 7);
            gl_lds16(kcb + kbase + (size_t)(kt * 64 + row) * 128 + l * 8,
                     &Ks[bi][(ii * 256 + (tid & ~63)) * 8]);
        }
        #pragma unroll
        for (int ii = 0; ii < 4; ++ii) {
            int s = ii * 256 + tid;
            int row = s >> 3, l = (s & 7) ^ (row & 7);
            gl_lds16(vt + vbase + (size_t)row * 4608 + kt * 64 + l * 8,
                     &Vl[bi][(ii * 256 + (tid & ~63)) * 8]);
        }
    };

    STAGE(0, ktA);
    __syncthreads();
    int cur = 0;
    for (int kt = ktA; kt < ktB; ++kt) {
        if (kt + 1 < ktB) STAGE(cur ^ 1, kt + 1);

        f32x16 S[2] = {};
        __builtin_amdgcn_s_setprio(1);
        #pragma unroll
        for (int s = 0; s < 8; ++s) {
            #pragma unroll
            for (int t = 0; t < 2; ++t) {
                int krow = t * 32 + q31;
                int blk = (2 * s + hi) ^ (krow & 7);
                short8v kf = __builtin_bit_cast(short8v,
                    *(const ushort8v*)&Ks[cur][krow * 128 + blk * 8]);
                S[t] = __builtin_amdgcn_mfma_f32_32x32x16_bf16(kf, qf[s], S[t], 0, 0, 0);
            }
        }
        __builtin_amdgcn_s_setprio(0);

        if (kt >= 64) {  // causal mask within the new segment
            const int kb0 = (kt - 64) * 64 + 4 * hi;
            #pragma unroll
            for (int r = 0; r < 16; ++r) {
                int koff = kb0 + (r & 3) + 8 * (r >> 2);
                if (koff > qrow)      S[0][r] = -3.0e38f;
                if (koff + 32 > qrow) S[1][r] = -3.0e38f;
            }
        }

        float mx = fmaxf(S[0][0], S[1][0]);
        #pragma unroll
        for (int r = 1; r < 16; ++r) mx = fmaxf(mx, fmaxf(S[0][r], S[1][r]));
        mx = fmaxf(mx, __shfl_xor(mx, 32, 64));

        if (__ballot(mx > m_i + 8.f)) {
            float mnew = fmaxf(m_i, mx);
            float alpha = __expf(m_i - mnew);
            m_i = mnew;
            l_i *= alpha;
            #pragma unroll
            for (int r = 0; r < 16; ++r) {
                float ar = __shfl(alpha, (r & 3) + 8 * (r >> 2) + 4 * hi, 64);
                O[0][r] *= ar; O[1][r] *= ar; O[2][r] *= ar; O[3][r] *= ar;
            }
        }
        #pragma unroll
        for (int r = 0; r < 16; ++r) {
            S[0][r] = __expf(S[0][r] - m_i); l_i += S[0][r];
            S[1][r] = __expf(S[1][r] - m_i); l_i += S[1][r];
        }

        __builtin_amdgcn_s_setprio(1);
        #pragma unroll
        for (int j = 0; j < 4; ++j) {
            const int t = j >> 1, r0 = 8 * (j & 1);
            u32 a0, a1, b0, b1;
            asm("v_cvt_pk_bf16_f32 %0, %1, %2" : "=v"(a0) : "v"(S[t][r0+0]), "v"(S[t][r0+1]));
            asm("v_cvt_pk_bf16_f32 %0, %1, %2" : "=v"(a1) : "v"(S[t][r0+2]), "v"(S[t][r0+3]));
            asm("v_cvt_pk_bf16_f32 %0, %1, %2" : "=v"(b0) : "v"(S[t][r0+4]), "v"(S[t][r0+5]));
            asm("v_cvt_pk_bf16_f32 %0, %1, %2" : "=v"(b1) : "v"(S[t][r0+6]), "v"(S[t][r0+7]));
            asm("v_permlane32_swap_b32 %0, %1" : "+v"(a0), "+v"(b0));
            asm("v_permlane32_swap_b32 %0, %1" : "+v"(a1), "+v"(b1));
            u32x4v pw = {a0, a1, b0, b1};
            short8v pf = __builtin_bit_cast(short8v, pw);
            #pragma unroll
            for (int od = 0; od < 4; ++od) {
                int vrow = od * 32 + q31;
                int blk = (2 * j + hi) ^ (vrow & 7);
                short8v vf = __builtin_bit_cast(short8v,
                    *(const ushort8v*)&Vl[cur][vrow * 64 + blk * 8]);
                O[od] = __builtin_amdgcn_mfma_f32_32x32x16_bf16(pf, vf, O[od], 0, 0, 0);
            }
        }
        __builtin_amdgcn_s_setprio(0);

        __syncthreads();
        cur ^= 1;
    }

    // partial epilogue: unnormalized O (bf16) + (m, l)
    float lt = l_i + __shfl_xor(l_i, 32, 64);
    u16* Op = sp ? Op1 : Op0;
    const size_t pbase = ((size_t)bh * 4 + qt2) * 16384;
    #pragma unroll
    for (int r = 0; r < 16; ++r) {
        int qoff = (r & 3) + 8 * (r >> 2) + 4 * hi;
        size_t rowb = pbase + (size_t)(w * 32 + qoff) * 128 + q31;
        Op[rowb +  0] = f2bf(O[0][r]);
        Op[rowb + 32] = f2bf(O[1][r]);
        Op[rowb + 64] = f2bf(O[2][r]);
        Op[rowb + 96] = f2bf(O[3][r]);
    }
    if (hi == 0) {
        int qg = ((sp * 256 + bh * 4 + qt2) * 128 + w * 32 + q31);
        mlp[qg * 2 + 0] = m_i;
        mlp[qg * 2 + 1] = lt;
    }
}

// ---------------------------------------------------------------------------
// combine (blocks 0..255) + Wo convert (blocks 256..2303) in one dispatch.
// ---------------------------------------------------------------------------
__global__ __launch_bounds__(256) void combine_conv_kernel(
    const u16* __restrict__ Op0, const u16* __restrict__ Op1,
    const float* __restrict__ mlp, u16* __restrict__ yb,
    const float* __restrict__ Wo, u16* __restrict__ wb3) {
    if (blockIdx.x >= 256) {
        const int idx = (blockIdx.x - 256) * 256 + threadIdx.x;
        const float* p = Wo + (size_t)idx * 8;
        f32x4 a = *(const f32x4*)p, b = *(const f32x4*)(p + 4);
        ushort8v o;
        o[0]=f2bf(a[0]); o[1]=f2bf(a[1]); o[2]=f2bf(a[2]); o[3]=f2bf(a[3]);
        o[4]=f2bf(b[0]); o[5]=f2bf(b[1]); o[6]=f2bf(b[2]); o[7]=f2bf(b[3]);
        *(ushort8v*)(wb3 + (size_t)idx * 8) = o;
        return;
    }
    const int p = blockIdx.x;
    const int bh = p >> 2, qt2 = p & 3;
    const int b = bh >> 4, h = bh & 15;
    const int q = threadIdx.x >> 1, dh = threadIdx.x & 1;
    const int base = (bh * 4 + qt2) * 128 + q;
    float m0 = mlp[base * 2], l0 = mlp[base * 2 + 1];
    float m1 = mlp[(256 * 128 + base) * 2], l1 = mlp[(256 * 128 + base) * 2 + 1];
    float M = fmaxf(m0, m1);
    float a0 = __expf(m0 - M), a1 = __expf(m1 - M);
    float invL = 1.0f / (l0 * a0 + l1 * a1);
    a0 *= invL; a1 *= invL;
    const size_t pb = ((size_t)bh * 4 + qt2) * 16384 + (size_t)q * 128 + dh * 64;
    u16* dst = yb + ((size_t)(b * 512 + qt2 * 128 + q)) * 2048 + h * 128 + dh * 64;
    #pragma unroll
    for (int j = 0; j < 8; ++j) {
        ushort8v o0 = *(const ushort8v*)(Op0 + pb + j * 8);
        ushort8v o1 = *(const ushort8v*)(Op1 + pb + j * 8);
        ushort8v o;
        #pragma unroll
        for (int e = 0; e < 8; ++e)
            o[e] = f2bf(bf2f(o0[e]) * a0 + bf2f(o1[e]) * a1);
        *(ushort8v*)(dst + j * 8) = o;
    }
}

// ---------------------------------------------------------------------------
extern "C" void kernel_launch(void* const* d_in, const int* in_sizes, int n_in,
                              void* d_out, int out_size, void* d_ws, size_t ws_size,
                              hipStream_t stream) {
    (void)in_sizes; (void)n_in; (void)out_size; (void)ws_size;
    const float* x   = (const float*)d_in[0];
    const int*   kq  = (const int*)d_in[1];
    const int*   vq  = (const int*)d_in[2];
    const float* ks  = (const float*)d_in[3];
    const float* vs  = (const float*)d_in[4];
    const float* Wq  = (const float*)d_in[5];
    const float* Wk  = (const float*)d_in[6];
    const float* Wv  = (const float*)d_in[7];
    const float* Wo  = (const float*)d_in[8];

    float* out  = (float*)d_out;
    float* y_o  = out;
    float* oktq = out + 4194304;
    float* ovtq = out + 37748736;
    float* oksc = out + 71303168;
    float* ovsc = out + 71565312;
    float* mlp  = out;   // y region is free until the final GEMM

    char* wsb = (char*)d_ws;
    u16* kcb = (u16*)(wsb);                       // 75.5 MB: [64][4608][128]
    u16* vtb = (u16*)(wsb + 75497472);            // 75.5 MB: [64][128][4608]
    u16* xb  = (u16*)(wsb + 150994944);           // 8 MB; later Opart split-0
    u16* qbf = (u16*)(wsb + 159383552);           // 8 MB
    u16* vnb = (u16*)(wsb + 167772160);           // 8 MB; later Opart split-1
    u16* ybf = (u16*)(wsb + 176160768);           // 8 MB
    u16* wb3 = (u16*)(wsb + 184549376);           // 24 MB: [Wq*s; Wk; Wv] bf16

    const float rscale = 0.08838834764831845f;    // 1/sqrt(128)

    prep_cache_kernel<<<4096, 256, 0, stream>>>(kq, vq, ks, vs, kcb, vtb,
                                                oktq, ovtq, oksc, ovsc);
    convert4_kernel<<<8192, 256, 0, stream>>>(x, Wq, Wk, Wv, xb, wb3, rscale);
    gemm_qkv_kernel<<<1536, 256, 0, stream>>>(xb, wb3, qbf, kcb, vnb);
    quant_new_kernel<<<512, 256, 0, stream>>>(kcb, vnb, vtb,
                                              oktq, ovtq, oksc, ovsc);
    attn_kernel<<<512, 256, 0, stream>>>(qbf, kcb, vtb, xb, vnb, mlp);
    combine_conv_kernel<<<2304, 256, 0, stream>>>(xb, vnb, mlp, ybf, Wo, wb3);
    gemm_wo_kernel<<<512, 256, 0, stream>>>(ybf, wb3, y_o);
}